// Round 6
// baseline (422.563 us; speedup 1.0000x reference)
//
#include <hip/hip_runtime.h>

typedef unsigned short u16;
typedef __attribute__((ext_vector_type(8)))  short bf16x8;
typedef __attribute__((ext_vector_type(16))) float f32x16;

#define NROWS 131072
#define NMOL  2048
#define CIN   128
#define HDIM  1024
#define EMBSTRIDE 1152   // 9*128

#define KT1 (CIN  / 16)   // 8
#define NT  (HDIM / 32)   // 32

#define BM2 256
#define BN2 256
#define NRB (NROWS / BM2) // 512
#define NCB (HDIM  / BN2) // 4

// ---------- helpers ----------
__device__ __forceinline__ u16 f2bf(float f) {
    union { float f; unsigned u; } v; v.f = f;
    unsigned u = v.u;
    u += 0x7FFFu + ((u >> 16) & 1u);   // round-to-nearest-even
    return (u16)(u >> 16);
}

__device__ __forceinline__ float silu_f(float v) {
    float e = __expf(-v);
    return v * __builtin_amdgcn_rcpf(1.0f + e);
}

__device__ __forceinline__ f32x16 mfma32(bf16x8 a, bf16x8 b, f32x16 c) {
    return __builtin_amdgcn_mfma_f32_32x32x16_bf16(a, b, c, 0, 0, 0);
}

__device__ __forceinline__ void gload_lds16(const u16* g, u16* l) {
    __builtin_amdgcn_global_load_lds(
        (const __attribute__((address_space(1))) unsigned int*)g,
        (__attribute__((address_space(3))) unsigned int*)l,
        16, 0, 0);
}

// ---------- pre-pass: pack W (K x N fp32 row-major) into bf16 32x32x16 B-fragments ----------
// frag id = kt*NT + nt. lane l, elem j -> W[kt*16 + (l>>5)*8 + j][nt*32 + (l&31)]
__global__ void pack_w32(const float* __restrict__ W, u16* __restrict__ dst, int K, int N) {
    int tid  = blockIdx.x * blockDim.x + threadIdx.x;
    int lane = tid & 63;
    int frag = tid >> 6;
    int NTl = N >> 5;
    int KTl = K >> 4;
    if (frag >= KTl * NTl) return;
    int kt = frag / NTl;
    int nt = frag - kt * NTl;
    int col  = (nt << 5) + (lane & 31);
    int krow = (kt << 4) + ((lane >> 5) << 3);
    __align__(16) u16 tmp[8];
    #pragma unroll
    for (int j = 0; j < 8; ++j) tmp[j] = f2bf(W[(size_t)(krow + j) * N + col]);
    *reinterpret_cast<uint4*>(dst + (size_t)tid * 8) = *reinterpret_cast<uint4*>(tmp);
}

// ---------- K1: h1 = silu(x @ W1 + b1), written as packed A-fragments ----------
// BM=64, 512 thr, 8 waves; wave w -> cols [w*128, w*128+128).
// h1f frag id = rt_global*64 + kt2 ; contents: lane l -> h1[rt*32 + (l&31)][kt2*16 + (l>>5)*8 + j]
__global__ __launch_bounds__(512, 2) void gemm1_pack(
    const float* __restrict__ emb,
    const u16*  __restrict__ w1f,
    const float* __restrict__ b1,
    u16* __restrict__ h1f)
{
    __shared__ u16 x_lds[64][CIN + 8];       // 17.4 KB
    __shared__ u16 h1_lds[64][HDIM + 8];     // 132 KB

    const int tid  = threadIdx.x;
    const int lane = tid & 63;
    const int w    = tid >> 6;
    const int l31  = lane & 31;
    const int lhi  = lane >> 5;
    const int row0 = blockIdx.x * 64;

    // stage x tile as bf16
    {
        int r   = tid >> 3;
        int seg = tid & 7;
        const float4* s4 = reinterpret_cast<const float4*>(
            emb + (size_t)(row0 + r) * EMBSTRIDE + seg * 16);
        __align__(16) u16 u[16];
        #pragma unroll
        for (int i = 0; i < 4; ++i) {
            float4 f = s4[i];
            u[i*4+0] = f2bf(f.x); u[i*4+1] = f2bf(f.y);
            u[i*4+2] = f2bf(f.z); u[i*4+3] = f2bf(f.w);
        }
        uint4* d = reinterpret_cast<uint4*>(&x_lds[r][seg * 16]);
        d[0] = reinterpret_cast<uint4*>(u)[0];
        d[1] = reinterpret_cast<uint4*>(u)[1];
    }

    auto LDB1 = [&](int kt, bf16x8* b) {
        #pragma unroll
        for (int nti = 0; nti < 4; ++nti)
            b[nti] = *reinterpret_cast<const bf16x8*>(
                w1f + (((size_t)kt * NT + 4 * w + nti) * 64 + lane) * 8);
    };

    bf16x8 bC[4], bN[4];
    LDB1(0, bC);
    __syncthreads();

    f32x16 acc1[2][4];
    #pragma unroll
    for (int mt = 0; mt < 2; ++mt)
        #pragma unroll
        for (int nti = 0; nti < 4; ++nti)
            #pragma unroll
            for (int r = 0; r < 16; ++r) acc1[mt][nti][r] = 0.0f;

    #pragma unroll
    for (int kt = 0; kt < KT1; ++kt) {
        if (kt + 1 < KT1) LDB1(kt + 1, bN);
        bf16x8 a[2];
        #pragma unroll
        for (int mt = 0; mt < 2; ++mt)
            a[mt] = *reinterpret_cast<const bf16x8*>(
                &x_lds[mt*32 + l31][kt*16 + (lhi << 3)]);
        #pragma unroll
        for (int nti = 0; nti < 4; ++nti)
            #pragma unroll
            for (int mt = 0; mt < 2; ++mt)
                acc1[mt][nti] = mfma32(a[mt], bC[nti], acc1[mt][nti]);
        if (kt + 1 < KT1) {
            #pragma unroll
            for (int i = 0; i < 4; ++i) bC[i] = bN[i];
        }
    }

    // silu -> bf16 -> h1_lds  (C/D: col=lane&31, row=(r&3)+8*(r>>2)+4*lhi)
    #pragma unroll
    for (int nti = 0; nti < 4; ++nti) {
        int col = w*128 + nti*32 + l31;
        float bias = b1[col];
        #pragma unroll
        for (int mt = 0; mt < 2; ++mt)
            #pragma unroll
            for (int r = 0; r < 16; ++r) {
                int row = mt*32 + (r & 3) + 8*(r >> 2) + 4*lhi;
                h1_lds[row][col] = f2bf(silu_f(acc1[mt][nti][r] + bias));
            }
    }
    // pack: wave reads back ITS OWN cols (kt2 = 8w..8w+7) in A-frag order -> global
    // (no barrier needed: within-wave ds_write -> ds_read ordering via lgkmcnt)
    const size_t rt0 = (size_t)blockIdx.x * 2;
    #pragma unroll
    for (int rtl = 0; rtl < 2; ++rtl)
        #pragma unroll
        for (int j = 0; j < 8; ++j) {
            int kt2 = w * 8 + j;
            bf16x8 v = *reinterpret_cast<const bf16x8*>(
                &h1_lds[rtl*32 + l31][kt2*16 + (lhi << 3)]);
            *reinterpret_cast<bf16x8*>(
                h1f + ((rt0 + rtl)*64 + kt2)*512 + lane*8) = v;
        }
}

// ---------- K2: h2 = silu(h1 @ W2 + b2), fold W3 -> per-row energy partials ----------
// BM2=256 x BN2=256, K=1024. 8 waves: rg = w>>1 (4 x 64 rows), cg = w&1 (2 x 128 cols).
// LDS: double-buffered 4-kt chunk, dense frag layout [piece 0..63][lane*16B]:
//   piece p<32 : A  (ktl = p>>3, rt = p&7)
//   piece p>=32: B  (ktl = (p-32)>>3, ntl = (p-32)&7)
__global__ __launch_bounds__(512, 2) void gemm2_energy(
    const u16*  __restrict__ h1f,
    const u16*  __restrict__ w2f,
    const float* __restrict__ b2,
    const float* __restrict__ w3,
    float* __restrict__ e_part)
{
    __shared__ u16 ab[2][64 * 512];          // 2 x 64 KB = 128 KB

    const int tid  = threadIdx.x;
    const int lane = tid & 63;
    const int w    = tid >> 6;
    const int l31  = lane & 31;
    const int lhi  = lane >> 5;
    const int rg   = w >> 1;
    const int cg   = w & 1;

    // bijective swizzle: 4 cb-blocks of one rb land on the same XCD (wgid % 8)
    const int wg = blockIdx.x;
    const int rb = (wg & 7) + 8 * ((wg >> 3) >> 2);
    const int cb = (wg >> 3) & 3;

    auto issue_chunk = [&](int kc, int b) {
        if (w < 4) {
            // A-waves: ktl = w, rt = i
            #pragma unroll
            for (int i = 0; i < 8; ++i) {
                const u16* src = h1f
                    + (((size_t)rb * 8 + i) * 64 + (size_t)(kc * 4 + w)) * 512
                    + lane * 8;
                gload_lds16(src, &ab[b][(size_t)(w*8 + i) * 512 + lane * 8]);
            }
        } else {
            // B-waves: ktl = w-4, ntl = i
            #pragma unroll
            for (int i = 0; i < 8; ++i) {
                const u16* src = w2f
                    + ((size_t)((kc * 4 + (w - 4)) * 32 + cb * 8 + i)) * 512
                    + lane * 8;
                gload_lds16(src, &ab[b][(size_t)(32 + (w-4)*8 + i) * 512 + lane * 8]);
            }
        }
    };

    f32x16 acc[2][4];
    #pragma unroll
    for (int mt = 0; mt < 2; ++mt)
        #pragma unroll
        for (int nti = 0; nti < 4; ++nti)
            #pragma unroll
            for (int r = 0; r < 16; ++r) acc[mt][nti][r] = 0.0f;

    issue_chunk(0, 0);
    __syncthreads();   // drains vmcnt(0): chunk 0 in LDS

    for (int kc = 0; kc < 16; ++kc) {
        const int b = kc & 1;
        if (kc + 1 < 16) issue_chunk(kc + 1, b ^ 1);
        #pragma unroll
        for (int ktl = 0; ktl < 4; ++ktl) {
            bf16x8 A0 = *reinterpret_cast<const bf16x8*>(&ab[b][(size_t)(ktl*8 + rg*2    ) * 512 + lane*8]);
            bf16x8 A1 = *reinterpret_cast<const bf16x8*>(&ab[b][(size_t)(ktl*8 + rg*2 + 1) * 512 + lane*8]);
            bf16x8 B0 = *reinterpret_cast<const bf16x8*>(&ab[b][(size_t)(32 + ktl*8 + cg*4 + 0) * 512 + lane*8]);
            bf16x8 B1 = *reinterpret_cast<const bf16x8*>(&ab[b][(size_t)(32 + ktl*8 + cg*4 + 1) * 512 + lane*8]);
            bf16x8 B2 = *reinterpret_cast<const bf16x8*>(&ab[b][(size_t)(32 + ktl*8 + cg*4 + 2) * 512 + lane*8]);
            bf16x8 B3 = *reinterpret_cast<const bf16x8*>(&ab[b][(size_t)(32 + ktl*8 + cg*4 + 3) * 512 + lane*8]);
            acc[0][0] = mfma32(A0, B0, acc[0][0]);
            acc[1][0] = mfma32(A1, B0, acc[1][0]);
            acc[0][1] = mfma32(A0, B1, acc[0][1]);
            acc[1][1] = mfma32(A1, B1, acc[1][1]);
            acc[0][2] = mfma32(A0, B2, acc[0][2]);
            acc[1][2] = mfma32(A1, B2, acc[1][2]);
            acc[0][3] = mfma32(A0, B3, acc[0][3]);
            acc[1][3] = mfma32(A1, B3, acc[1][3]);
        }
        __syncthreads();   // drains vmcnt (next chunk staged) + lgkm; swap buffers
    }

    // epilogue: silu + dot W3, reduce over the wave's 128 cols
    float e_lane[32];
    #pragma unroll
    for (int i = 0; i < 32; ++i) e_lane[i] = 0.0f;

    #pragma unroll
    for (int nti = 0; nti < 4; ++nti) {
        int col = cb*256 + cg*128 + nti*32 + l31;
        float bias = b2[col];
        float w3v  = w3[col];
        #pragma unroll
        for (int mt = 0; mt < 2; ++mt)
            #pragma unroll
            for (int r = 0; r < 16; ++r) {
                float s = silu_f(acc[mt][nti][r] + bias);
                e_lane[mt*16 + r] += s * w3v;
            }
    }

    #pragma unroll
    for (int off = 1; off < 32; off <<= 1)
        #pragma unroll
        for (int i = 0; i < 32; ++i)
            e_lane[i] += __shfl_xor(e_lane[i], off, 64);

    if (l31 == 0) {
        const size_t slab = (size_t)(cb*2 + cg) * NROWS;
        #pragma unroll
        for (int mt = 0; mt < 2; ++mt)
            #pragma unroll
            for (int r = 0; r < 16; ++r) {
                int row = rg*64 + mt*32 + (r & 3) + 8*(r >> 2) + 4*lhi;
                e_part[slab + (size_t)rb*256 + row] = e_lane[mt*16 + r];
            }
    }
}

// ---------- deterministic segment sum over sorted batch, folding 8 partial slabs + b3 ----------
__global__ void segsum(const float* __restrict__ e_part,
                       const int* __restrict__ batch,
                       const float* __restrict__ b3,
                       float* __restrict__ out)
{
    int mol  = blockIdx.x;
    int lane = threadIdx.x;          // 64 threads

    int lo = 0, hi = NROWS;
    while (lo < hi) { int mid = (lo + hi) >> 1; if (batch[mid] < mol)     lo = mid + 1; else hi = mid; }
    int start = lo;
    lo = start; hi = NROWS;
    while (lo < hi) { int mid = (lo + hi) >> 1; if (batch[mid] < mol + 1) lo = mid + 1; else hi = mid; }
    int end = lo;

    float b3v = b3[0];
    float s = 0.0f;
    for (int i = start + lane; i < end; i += 64) {
        float v = b3v;
        #pragma unroll
        for (int sl = 0; sl < 8; ++sl) v += e_part[(size_t)sl * NROWS + i];
        s += v;
    }
    #pragma unroll
    for (int off = 32; off; off >>= 1) s += __shfl_xor(s, off, 64);
    if (lane == 0) out[mol] = s;
}

// ---------- launch ----------
extern "C" void kernel_launch(void* const* d_in, const int* in_sizes, int n_in,
                              void* d_out, int out_size, void* d_ws, size_t ws_size,
                              hipStream_t stream) {
    const float* emb = (const float*)d_in[0];
    const float* W1  = (const float*)d_in[1];
    const float* b1  = (const float*)d_in[2];
    const float* W2  = (const float*)d_in[3];
    const float* b2  = (const float*)d_in[4];
    const float* W3  = (const float*)d_in[5];
    const float* b3  = (const float*)d_in[6];
    const int*   batch = (const int*)d_in[7];

    char* ws = (char*)d_ws;
    u16*   w1f    = (u16*)ws;                                  // 256 KB
    u16*   w2f    = (u16*)(ws + 262144);                       // 2 MB
    u16*   h1f    = (u16*)(ws + 2359296);                      // 256 MB
    float* e_part = (float*)(ws + 2359296 + 268435456);        // 4 MB

    pack_w32<<<64,  256, 0, stream>>>(W1, w1f, CIN,  HDIM);
    pack_w32<<<512, 256, 0, stream>>>(W2, w2f, HDIM, HDIM);
    gemm1_pack<<<NROWS / 64, 512, 0, stream>>>(emb, w1f, b1, h1f);
    gemm2_energy<<<NRB * NCB, 512, 0, stream>>>(h1f, w2f, b2, W3, e_part);
    segsum<<<NMOL, 64, 0, stream>>>(e_part, batch, b3, (float*)d_out);
}